// Round 5
// baseline (4079.581 us; speedup 1.0000x reference)
//
#include <hip/hip_runtime.h>
#include <hip/hip_bf16.h>
#include <math.h>

#define B_   128
#define T_   2048
#define DIN  64
#define H_   128
#define WH_  256
#define WY_  256
#define DOUT 64

typedef __attribute__((ext_vector_type(8))) short short8;
typedef __attribute__((ext_vector_type(4))) float floatx4;

// Raw barrier: wait LDS ops only (global stores stay in flight).
__device__ __forceinline__ void bar_lds() {
    asm volatile("s_waitcnt lgkmcnt(0)\n\ts_barrier" ::: "memory");
}

__device__ __forceinline__ short bf16_hi(float f) {
    __hip_bfloat16 h = __float2bfloat16(f);
    return *reinterpret_cast<short*>(&h);
}
__device__ __forceinline__ float bf16_val(short s) {
    __hip_bfloat16 h = *reinterpret_cast<__hip_bfloat16*>(&s);
    return __bfloat162float(h);
}

// GEMV1 partial: K=192 interleaved, k = kh*4 + jj*8 + e (bank-disjoint halves)
__device__ __forceinline__ float gemv1_acc(const float* hx, const float* W, int kh) {
    float a0 = 0.f, a1 = 0.f, a2 = 0.f, a3 = 0.f;
    const float* base = hx + kh * 4;
#pragma unroll
    for (int jj = 0; jj < 24; ++jj) {
        const float4 h4 = *(const float4*)(base + jj * 8);
        a0 += h4.x * W[jj * 4 + 0];
        a1 += h4.y * W[jj * 4 + 1];
        a2 += h4.z * W[jj * 4 + 2];
        a3 += h4.w * W[jj * 4 + 3];
    }
    return (a0 + a1) + (a2 + a3);
}

// GEMV2 partial: K=256 interleaved, k = kq*4 + jj*16 + e (bank-disjoint quarters)
__device__ __forceinline__ float gemv2_acc(const float* sl, const float* W, int kq) {
    float a0 = 0.f, a1 = 0.f, a2 = 0.f, a3 = 0.f;
    const float* base = sl + kq * 4;
#pragma unroll
    for (int jj = 0; jj < 16; ++jj) {
        const float4 s4 = *(const float4*)(base + jj * 16);
        a0 += s4.x * W[jj * 4 + 0];
        a1 += s4.y * W[jj * 4 + 1];
        a2 += s4.z * W[jj * 4 + 2];
        a3 += s4.w * W[jj * 4 + 3];
    }
    return (a0 + a1) + (a2 + a3);
}

// ---------------- Phase 1: sequential recurrence, fp32 VALU ----------------
// 64 WGs x 512 threads, 2 rows/WG (rA, rB) phase-offset by a half-step.
// 2 barriers advance BOTH rows one step. All reductions intra-wave (shfl).
__global__ __launch_bounds__(512, 2) void rnn_phase1(
    const float* __restrict__ x,
    const float* __restrict__ hW1, const float* __restrict__ hb1,
    const float* __restrict__ hW2, const float* __restrict__ hb2,
    __hip_bfloat16* __restrict__ HallB,  // [T_*B_, H_] bf16
    float* __restrict__ outF)            // d_out; hfinal tail fp32
{
    const int rA   = blockIdx.x * 2;
    const int rB   = rA + 1;
    const int tid  = threadIdx.x;
    const int wave = tid >> 6, lane = tid & 63;

    __shared__ float hxA[192], hxB[192];   // [0..127]=h, [128..191]=x_t
    __shared__ float slA[256], slB[256];

    const int f1 = wave * 32 + (lane & 31), kh = lane >> 5;
    const int f2 = wave * 16 + (lane & 15), kq = lane >> 4;

    // Weights in k-interleaved order (reg indices compile-time)
    float W1r[96];
#pragma unroll
    for (int jj = 0; jj < 24; ++jj)
        *(float4*)&W1r[jj * 4] = *(const float4*)&hW1[f1 * 192 + kh * 4 + jj * 8];
    float W2r[64];
#pragma unroll
    for (int jj = 0; jj < 16; ++jj)
        *(float4*)&W2r[jj * 4] = *(const float4*)&hW2[f2 * 256 + kq * 4 + jj * 16];

    const float b1v = hb1[f1];
    const float b2v = hb2[f2];

    if (tid < 128) { hxA[tid] = 0.f; hxB[tid] = 0.f; }
    float xAreg = 0.f, xBreg = 0.f;
    if (tid >= 448) {                       // row A x-handler
        const int l = tid - 448;
        const long xb = (long)rA * (T_ * DIN);
        hxA[128 + l] = x[xb + l];
        xAreg        = x[xb + DIN + l];
    }
    if (tid >= 384 && tid < 448) {          // row B x-handler
        const int l = tid - 384;
        const long xb = (long)rB * (T_ * DIN);
        hxB[128 + l] = x[xb + l];
        xBreg        = x[xb + DIN + l];
    }
    __syncthreads();

    // Prologue: half-step for B -> slB(0)
    {
        float v = gemv1_acc(hxB, W1r, kh);
        v += __shfl_xor(v, 32, 64);
        v += b1v;
        const float s = v / (1.f + expf(-v));
        if (lane < 32) slB[f1] = s;
    }
    bar_lds();

    for (int t = 0; t < T_; ++t) {
        // ---- Phase A: GEMV1(A,t)->slA  ||  GEMV2(B,t)->hB,Hall  || xB install
        {
            float v = gemv1_acc(hxA, W1r, kh);
            v += __shfl_xor(v, 32, 64);
            v += b1v;
            const float s = v / (1.f + expf(-v));

            float hv = gemv2_acc(slB, W2r, kq);
            hv += __shfl_xor(hv, 16, 64);
            hv += __shfl_xor(hv, 32, 64);
            hv += b2v;

            if (lane < 32) slA[f1] = s;
            if (lane < 16) {
                hxB[f2] = hv;
                HallB[((long)t * B_ + rB) * H_ + f2] = __float2bfloat16(hv);
            }
            if (tid >= 384 && tid < 448) {
                const int l = tid - 384;
                hxB[128 + l] = xBreg;       // x for B step t+1
                const int tn = (t + 2 < T_) ? (t + 2) : (T_ - 1);
                xBreg = x[(long)rB * (T_ * DIN) + (long)tn * DIN + l];
            }
        }
        bar_lds();

        // ---- Phase B: GEMV1(B,t+1)->slB  ||  GEMV2(A,t)->hA,Hall || xA install
        {
            float v = gemv1_acc(hxB, W1r, kh);
            v += __shfl_xor(v, 32, 64);
            v += b1v;
            const float s = v / (1.f + expf(-v));

            float hv = gemv2_acc(slA, W2r, kq);
            hv += __shfl_xor(hv, 16, 64);
            hv += __shfl_xor(hv, 32, 64);
            hv += b2v;

            if (lane < 32) slB[f1] = s;
            if (lane < 16) {
                hxA[f2] = hv;
                HallB[((long)t * B_ + rA) * H_ + f2] = __float2bfloat16(hv);
            }
            if (tid >= 448) {
                const int l = tid - 448;
                hxA[128 + l] = xAreg;       // x for A step t+1
                const int tn = (t + 2 < T_) ? (t + 2) : (T_ - 1);
                xAreg = x[(long)rA * (T_ * DIN) + (long)tn * DIN + l];
            }
        }
        bar_lds();
    }

    if (tid < 128) {
        const long tail = (long)B_ * T_ * DOUT;
        outF[tail + (long)rA * H_ + tid] = hxA[tid];
        outF[tail + (long)rB * H_ + tid] = hxB[tid];
    }
}

// -------- pre-split y-weights into MFMA-frag-linear bf16 hi/lo -------------
__global__ __launch_bounds__(256) void presplit(
    const float* __restrict__ yW1, const float* __restrict__ yW2,
    short* __restrict__ Y1f, short* __restrict__ Y2f)
{
    const int i = blockIdx.x * 256 + threadIdx.x;
    if (i < 32768) {
        const int j = i & 7, lane = (i >> 3) & 63, ks = (i >> 9) & 3, nt = i >> 11;
        const float v = yW1[(nt * 16 + (lane & 15)) * 128 + (lane >> 4) * 8 + ks * 32 + j];
        const short h = bf16_hi(v);
        Y1f[i]         = h;
        Y1f[32768 + i] = bf16_hi(v - bf16_val(h));
    }
    if (i < 16384) {
        const int j = i & 7, lane = (i >> 3) & 63, ks = (i >> 9) & 7, nt2 = i >> 12;
        const float v = yW2[(nt2 * 16 + (lane & 15)) * 256 + (lane >> 4) * 8 + ks * 32 + j];
        const short h = bf16_hi(v);
        Y2f[i]         = h;
        Y2f[16384 + i] = bf16_hi(v - bf16_val(h));
    }
}

// ---------------- Phase 2: y-MLP via MFMA, hi/lo split ---------------------
// 2048 WGs x 4 waves; each wave one PAIR of 16-row tiles (32 rows). No iter loop.
__global__ __launch_bounds__(256) void rnn_phase2(
    const __hip_bfloat16* __restrict__ HallB,
    const float* __restrict__ yb1, const float* __restrict__ yb2,
    const short* __restrict__ Y1f, const short* __restrict__ Y2f,
    float* __restrict__ out)
{
    __shared__ short u_lds[4][2][16 * 256];   // per-wave 2 tiles x 8KB

    const int tid  = threadIdx.x;
    const int wave = tid >> 6, lane = tid & 63;
    const int l15  = lane & 15, lg = lane >> 4;
    const long pair = (long)blockIdx.x * 4 + wave;   // 0..8191
    const long r0   = pair * 32;
    const floatx4 zero4 = {0.f, 0.f, 0.f, 0.f};
    const short* Hs = (const short*)HallB;

    // A-frags for both tiles (8 independent global loads, issued up front)
    short8 aH[2][4];
#pragma unroll
    for (int p = 0; p < 2; ++p)
#pragma unroll
        for (int ks = 0; ks < 4; ++ks)
            aH[p][ks] = *(const short8*)(Hs + (r0 + p * 16 + l15) * 128 + lg * 8 + ks * 32);

    // ---- GEMM1 + silu -> u (bf16) in LDS, XOR-swizzled
#pragma unroll
    for (int nt = 0; nt < 16; ++nt) {
        floatx4 accA = zero4, accB = zero4;
#pragma unroll
        for (int ks = 0; ks < 4; ++ks) {
            const short8 bhi = *(const short8*)(Y1f + ((nt * 4 + ks) * 512 + lane * 8));
            const short8 blo = *(const short8*)(Y1f + 32768 + ((nt * 4 + ks) * 512 + lane * 8));
            accA = __builtin_amdgcn_mfma_f32_16x16x32_bf16(aH[0][ks], bhi, accA, 0, 0, 0);
            accA = __builtin_amdgcn_mfma_f32_16x16x32_bf16(aH[0][ks], blo, accA, 0, 0, 0);
            accB = __builtin_amdgcn_mfma_f32_16x16x32_bf16(aH[1][ks], bhi, accB, 0, 0, 0);
            accB = __builtin_amdgcn_mfma_f32_16x16x32_bf16(aH[1][ks], blo, accB, 0, 0, 0);
        }
        const int col  = nt * 16 + l15;
        const float bias = yb1[col];
#pragma unroll
        for (int r = 0; r < 4; ++r) {
            const int row = lg * 4 + r;
            int byte = row * 512 + col * 2;
            byte ^= ((row & 7) << 4);
            float v = accA[r] + bias;
            *(short*)((char*)u_lds[wave][0] + byte) = bf16_hi(v / (1.f + __expf(-v)));
            v = accB[r] + bias;
            *(short*)((char*)u_lds[wave][1] + byte) = bf16_hi(v / (1.f + __expf(-v)));
        }
    }
    asm volatile("s_waitcnt lgkmcnt(0)" ::: "memory");

    // ---- GEMM2
    floatx4 acc2A[4] = {zero4, zero4, zero4, zero4};
    floatx4 acc2B[4] = {zero4, zero4, zero4, zero4};
#pragma unroll
    for (int ks = 0; ks < 8; ++ks) {
        int byte = l15 * 512 + (lg * 8 + ks * 32) * 2;
        byte ^= ((l15 & 7) << 4);
        const short8 aUa = *(const short8*)((char*)u_lds[wave][0] + byte);
        const short8 aUb = *(const short8*)((char*)u_lds[wave][1] + byte);
#pragma unroll
        for (int nt = 0; nt < 4; ++nt) {
            const short8 bhi = *(const short8*)(Y2f + ((nt * 8 + ks) * 512 + lane * 8));
            const short8 blo = *(const short8*)(Y2f + 16384 + ((nt * 8 + ks) * 512 + lane * 8));
            acc2A[nt] = __builtin_amdgcn_mfma_f32_16x16x32_bf16(aUa, bhi, acc2A[nt], 0, 0, 0);
            acc2A[nt] = __builtin_amdgcn_mfma_f32_16x16x32_bf16(aUa, blo, acc2A[nt], 0, 0, 0);
            acc2B[nt] = __builtin_amdgcn_mfma_f32_16x16x32_bf16(aUb, bhi, acc2B[nt], 0, 0, 0);
            acc2B[nt] = __builtin_amdgcn_mfma_f32_16x16x32_bf16(aUb, blo, acc2B[nt], 0, 0, 0);
        }
    }

    // ---- epilogue: bias + fp32 store (D: col=l15+16nt, row=lg*4+r)
#pragma unroll
    for (int nt = 0; nt < 4; ++nt) {
        const int col  = nt * 16 + l15;
        const float bias = yb2[col];
#pragma unroll
        for (int r = 0; r < 4; ++r) {
            {
                const long R  = r0 + lg * 4 + r;
                const long bb = R & (B_ - 1);
                const long tt = R >> 7;
                out[bb * (T_ * DOUT) + tt * DOUT + col] = acc2A[nt][r] + bias;
            }
            {
                const long R  = r0 + 16 + lg * 4 + r;
                const long bb = R & (B_ - 1);
                const long tt = R >> 7;
                out[bb * (T_ * DOUT) + tt * DOUT + col] = acc2B[nt][r] + bias;
            }
        }
    }
}

extern "C" void kernel_launch(void* const* d_in, const int* in_sizes, int n_in,
                              void* d_out, int out_size, void* d_ws, size_t ws_size,
                              hipStream_t stream) {
    const float* x   = (const float*)d_in[0];
    const float* hW1 = (const float*)d_in[1];
    const float* hb1 = (const float*)d_in[2];
    const float* hW2 = (const float*)d_in[3];
    const float* hb2 = (const float*)d_in[4];
    const float* yW1 = (const float*)d_in[5];
    const float* yb1 = (const float*)d_in[6];
    const float* yW2 = (const float*)d_in[7];
    const float* yb2 = (const float*)d_in[8];

    float* out = (float*)d_out;
    __hip_bfloat16* HallB = (__hip_bfloat16*)d_ws;               // 64 MiB
    const size_t hallBytes = (size_t)T_ * B_ * H_ * sizeof(__hip_bfloat16);
    short* Y1f = (short*)((char*)d_ws + hallBytes);              // 128 KB (hi+lo)
    short* Y2f = Y1f + 65536;                                    // 64 KB

    rnn_phase1<<<64, 512, 0, stream>>>(x, hW1, hb1, hW2, hb2, HallB, out);
    presplit<<<128, 256, 0, stream>>>(yW1, yW2, Y1f, Y2f);
    rnn_phase2<<<2048, 256, 0, stream>>>(HallB, yb1, yb2, Y1f, Y2f, out);
}

// Round 6
// 2210.110 us; speedup vs baseline: 1.8459x; 1.8459x over previous
//
#include <hip/hip_runtime.h>
#include <hip/hip_bf16.h>
#include <math.h>

#define B_   128
#define T_   2048
#define DIN  64
#define H_   128
#define WH_  256
#define WY_  256
#define DOUT 64

typedef __attribute__((ext_vector_type(8))) short short8;
typedef __attribute__((ext_vector_type(4))) float floatx4;

// Raw barrier: wait LDS ops only (global stores stay in flight).
__device__ __forceinline__ void bar_lds() {
    asm volatile("s_waitcnt lgkmcnt(0)\n\ts_barrier" ::: "memory");
}

__device__ __forceinline__ short bf16_hi(float f) {
    __hip_bfloat16 h = __float2bfloat16(f);
    return *reinterpret_cast<short*>(&h);
}
__device__ __forceinline__ float bf16_val(short s) {
    __hip_bfloat16 h = *reinterpret_cast<__hip_bfloat16*>(&s);
    return __bfloat162float(h);
}

// Butterfly sums via CDNA4 permlane swaps (VALU-only, no DS latency).
// v_permlane32_swap: D=[D.h0,S.h0], S=[D.h1,S.h1]  -> d+s == v + shfl_xor(v,32)
__device__ __forceinline__ float red_xor32(float v) {
    float d = v, s = v;
    asm volatile("v_permlane32_swap_b32 %0, %1" : "+v"(d), "+v"(s));
    return d + s;
}
// v_permlane16_swap: D=[D.r0,S.r0,D.r2,S.r2], S=[D.r1,S.r1,D.r3,S.r3]
//   -> d+s == v + shfl_xor(v,16)
__device__ __forceinline__ float red_xor16(float v) {
    float d = v, s = v;
    asm volatile("v_permlane16_swap_b32 %0, %1" : "+v"(d), "+v"(s));
    return d + s;
}

// ---------------- Phase 1: sequential recurrence, fp32 VALU ----------------
// 128 WGs (1 batch row) x 512 threads. 2 phases (2 barriers) per step.
// GEMV1: f1 = wave*32+(lane&31), K-half kh=lane>>5, interleaved k=kh*4+jj*8+e
// GEMV2: f2 = wave*16+(lane&15), K-quarter kq=lane>>4, k=kq*4+jj*16+e
// Reductions entirely in VALU (permlane swaps). No partial-sum LDS arrays.
__global__ __launch_bounds__(512, 2) void rnn_phase1(
    const float* __restrict__ x,
    const float* __restrict__ hW1, const float* __restrict__ hb1,
    const float* __restrict__ hW2, const float* __restrict__ hb2,
    __hip_bfloat16* __restrict__ HallB,  // [T_*B_, H_] bf16
    float* __restrict__ outF)            // d_out; hfinal tail fp32
{
    const int b    = blockIdx.x;
    const int tid  = threadIdx.x;
    const int wave = tid >> 6, lane = tid & 63;

    __shared__ float hx[192];        // [0..127]=h fp32, [128..191]=x_t
    __shared__ float sl[256];

    const int f1 = wave * 32 + (lane & 31), kh = lane >> 5;
    const int f2 = wave * 16 + (lane & 15), kq = lane >> 4;

    // Weights in k-interleaved order (compile-time reg indices)
    float W1r[96];
#pragma unroll
    for (int jj = 0; jj < 24; ++jj)
        *(float4*)&W1r[jj * 4] = *(const float4*)&hW1[f1 * 192 + kh * 4 + jj * 8];
    float W2r[64];
#pragma unroll
    for (int jj = 0; jj < 16; ++jj)
        *(float4*)&W2r[jj * 4] = *(const float4*)&hW2[f2 * 256 + kq * 4 + jj * 16];

    const float b1v = hb1[f1];
    const float b2v = hb2[f2];

    if (tid < 128) hx[tid] = 0.f;
    float xreg = 0.f;
    if (tid >= 448) {
        const int l = tid - 448;
        const long xb = (long)b * (T_ * DIN);
        hx[128 + l] = x[xb + l];        // x_0
        xreg        = x[xb + DIN + l];  // x_1
    }
    __syncthreads();

    for (int t = 0; t < T_; ++t) {
        // ---- Phase A: GEMV1 + permlane reduce + silu -> sl
        {
            float a0 = 0.f, a1 = 0.f, a2 = 0.f, a3 = 0.f;
            const float* hp = &hx[kh * 4];    // 2 broadcast addrs/wave, bank-disjoint
#pragma unroll
            for (int jj = 0; jj < 24; ++jj) {
                const float4 h4 = *(const float4*)(hp + jj * 8);
                a0 += h4.x * W1r[jj * 4 + 0];
                a1 += h4.y * W1r[jj * 4 + 1];
                a2 += h4.z * W1r[jj * 4 + 2];
                a3 += h4.w * W1r[jj * 4 + 3];
            }
            float v = red_xor32((a0 + a1) + (a2 + a3));
            v += b1v;
            const float s = v / (1.f + expf(-v));
            if (lane < 32) sl[f1] = s;
        }
        bar_lds();

        // ---- Phase B: GEMV2 + permlane reduces -> h_new; Hall; x install
        {
            float c0 = 0.f, c1 = 0.f, c2 = 0.f, c3 = 0.f;
            const float* sp = &sl[kq * 4];    // 4 broadcast addrs/wave, bank-disjoint
#pragma unroll
            for (int jj = 0; jj < 16; ++jj) {
                const float4 s4 = *(const float4*)(sp + jj * 16);
                c0 += s4.x * W2r[jj * 4 + 0];
                c1 += s4.y * W2r[jj * 4 + 1];
                c2 += s4.z * W2r[jj * 4 + 2];
                c3 += s4.w * W2r[jj * 4 + 3];
            }
            float hv = red_xor16((c0 + c1) + (c2 + c3));
            hv = red_xor32(hv);
            hv += b2v;
            if (lane < 16) {
                hx[f2] = hv;                  // fp32 recurrent state
                HallB[((long)t * B_ + b) * H_ + f2] = __float2bfloat16(hv);
            }
            if (tid >= 448) {                 // x_{t+1} install + prefetch x_{t+2}
                const int l = tid - 448;
                hx[128 + l] = xreg;
                const int tn = (t + 2 < T_) ? (t + 2) : (T_ - 1);
                xreg = x[(long)b * (T_ * DIN) + (long)tn * DIN + l];
            }
        }
        bar_lds();
    }

    if (tid < 128)
        outF[(long)B_ * T_ * DOUT + (long)b * H_ + tid] = hx[tid];
}

// -------- pre-split y-weights into MFMA-frag-linear bf16 hi/lo -------------
__global__ __launch_bounds__(256) void presplit(
    const float* __restrict__ yW1, const float* __restrict__ yW2,
    short* __restrict__ Y1f, short* __restrict__ Y2f)
{
    const int i = blockIdx.x * 256 + threadIdx.x;
    if (i < 32768) {
        const int j = i & 7, lane = (i >> 3) & 63, ks = (i >> 9) & 3, nt = i >> 11;
        const float v = yW1[(nt * 16 + (lane & 15)) * 128 + (lane >> 4) * 8 + ks * 32 + j];
        const short h = bf16_hi(v);
        Y1f[i]         = h;
        Y1f[32768 + i] = bf16_hi(v - bf16_val(h));
    }
    if (i < 16384) {
        const int j = i & 7, lane = (i >> 3) & 63, ks = (i >> 9) & 7, nt2 = i >> 12;
        const float v = yW2[(nt2 * 16 + (lane & 15)) * 256 + (lane >> 4) * 8 + ks * 32 + j];
        const short h = bf16_hi(v);
        Y2f[i]         = h;
        Y2f[16384 + i] = bf16_hi(v - bf16_val(h));
    }
}

// ---------------- Phase 2: y-MLP via MFMA, hi/lo split ---------------------
// 2048 WGs x 4 waves; each wave one PAIR of 16-row tiles (32 rows).
__global__ __launch_bounds__(256) void rnn_phase2(
    const __hip_bfloat16* __restrict__ HallB,
    const float* __restrict__ yb1, const float* __restrict__ yb2,
    const short* __restrict__ Y1f, const short* __restrict__ Y2f,
    float* __restrict__ out)
{
    __shared__ short u_lds[4][2][16 * 256];   // per-wave 2 tiles x 8KB

    const int tid  = threadIdx.x;
    const int wave = tid >> 6, lane = tid & 63;
    const int l15  = lane & 15, lg = lane >> 4;
    const long pair = (long)blockIdx.x * 4 + wave;   // 0..8191
    const long r0   = pair * 32;
    const floatx4 zero4 = {0.f, 0.f, 0.f, 0.f};
    const short* Hs = (const short*)HallB;

    short8 aH[2][4];
#pragma unroll
    for (int p = 0; p < 2; ++p)
#pragma unroll
        for (int ks = 0; ks < 4; ++ks)
            aH[p][ks] = *(const short8*)(Hs + (r0 + p * 16 + l15) * 128 + lg * 8 + ks * 32);

    // ---- GEMM1 + silu -> u (bf16) in LDS, XOR-swizzled
#pragma unroll
    for (int nt = 0; nt < 16; ++nt) {
        floatx4 accA = zero4, accB = zero4;
#pragma unroll
        for (int ks = 0; ks < 4; ++ks) {
            const short8 bhi = *(const short8*)(Y1f + ((nt * 4 + ks) * 512 + lane * 8));
            const short8 blo = *(const short8*)(Y1f + 32768 + ((nt * 4 + ks) * 512 + lane * 8));
            accA = __builtin_amdgcn_mfma_f32_16x16x32_bf16(aH[0][ks], bhi, accA, 0, 0, 0);
            accA = __builtin_amdgcn_mfma_f32_16x16x32_bf16(aH[0][ks], blo, accA, 0, 0, 0);
            accB = __builtin_amdgcn_mfma_f32_16x16x32_bf16(aH[1][ks], bhi, accB, 0, 0, 0);
            accB = __builtin_amdgcn_mfma_f32_16x16x32_bf16(aH[1][ks], blo, accB, 0, 0, 0);
        }
        const int col  = nt * 16 + l15;
        const float bias = yb1[col];
#pragma unroll
        for (int r = 0; r < 4; ++r) {
            const int row = lg * 4 + r;
            int byte = row * 512 + col * 2;
            byte ^= ((row & 7) << 4);
            float v = accA[r] + bias;
            *(short*)((char*)u_lds[wave][0] + byte) = bf16_hi(v / (1.f + __expf(-v)));
            v = accB[r] + bias;
            *(short*)((char*)u_lds[wave][1] + byte) = bf16_hi(v / (1.f + __expf(-v)));
        }
    }
    asm volatile("s_waitcnt lgkmcnt(0)" ::: "memory");

    // ---- GEMM2
    floatx4 acc2A[4] = {zero4, zero4, zero4, zero4};
    floatx4 acc2B[4] = {zero4, zero4, zero4, zero4};
#pragma unroll
    for (int ks = 0; ks < 8; ++ks) {
        int byte = l15 * 512 + (lg * 8 + ks * 32) * 2;
        byte ^= ((l15 & 7) << 4);
        const short8 aUa = *(const short8*)((char*)u_lds[wave][0] + byte);
        const short8 aUb = *(const short8*)((char*)u_lds[wave][1] + byte);
#pragma unroll
        for (int nt = 0; nt < 4; ++nt) {
            const short8 bhi = *(const short8*)(Y2f + ((nt * 8 + ks) * 512 + lane * 8));
            const short8 blo = *(const short8*)(Y2f + 16384 + ((nt * 8 + ks) * 512 + lane * 8));
            acc2A[nt] = __builtin_amdgcn_mfma_f32_16x16x32_bf16(aUa, bhi, acc2A[nt], 0, 0, 0);
            acc2A[nt] = __builtin_amdgcn_mfma_f32_16x16x32_bf16(aUa, blo, acc2A[nt], 0, 0, 0);
            acc2B[nt] = __builtin_amdgcn_mfma_f32_16x16x32_bf16(aUb, bhi, acc2B[nt], 0, 0, 0);
            acc2B[nt] = __builtin_amdgcn_mfma_f32_16x16x32_bf16(aUb, blo, acc2B[nt], 0, 0, 0);
        }
    }

    // ---- epilogue: bias + fp32 store (D: col=l15+16nt, row=lg*4+r)
#pragma unroll
    for (int nt = 0; nt < 4; ++nt) {
        const int col  = nt * 16 + l15;
        const float bias = yb2[col];
#pragma unroll
        for (int r = 0; r < 4; ++r) {
            {
                const long R  = r0 + lg * 4 + r;
                const long bb = R & (B_ - 1);
                const long tt = R >> 7;
                out[bb * (T_ * DOUT) + tt * DOUT + col] = acc2A[nt][r] + bias;
            }
            {
                const long R  = r0 + 16 + lg * 4 + r;
                const long bb = R & (B_ - 1);
                const long tt = R >> 7;
                out[bb * (T_ * DOUT) + tt * DOUT + col] = acc2B[nt][r] + bias;
            }
        }
    }
}

extern "C" void kernel_launch(void* const* d_in, const int* in_sizes, int n_in,
                              void* d_out, int out_size, void* d_ws, size_t ws_size,
                              hipStream_t stream) {
    const float* x   = (const float*)d_in[0];
    const float* hW1 = (const float*)d_in[1];
    const float* hb1 = (const float*)d_in[2];
    const float* hW2 = (const float*)d_in[3];
    const float* hb2 = (const float*)d_in[4];
    const float* yW1 = (const float*)d_in[5];
    const float* yb1 = (const float*)d_in[6];
    const float* yW2 = (const float*)d_in[7];
    const float* yb2 = (const float*)d_in[8];

    float* out = (float*)d_out;
    __hip_bfloat16* HallB = (__hip_bfloat16*)d_ws;               // 64 MiB
    const size_t hallBytes = (size_t)T_ * B_ * H_ * sizeof(__hip_bfloat16);
    short* Y1f = (short*)((char*)d_ws + hallBytes);              // 128 KB (hi+lo)
    short* Y2f = Y1f + 65536;                                    // 64 KB

    rnn_phase1<<<128, 512, 0, stream>>>(x, hW1, hb1, hW2, hb2, HallB, out);
    presplit<<<128, 256, 0, stream>>>(yW1, yW2, Y1f, Y2f);
    rnn_phase2<<<2048, 256, 0, stream>>>(HallB, yb1, yb2, Y1f, Y2f, out);
}